// Round 1
// baseline (412.553 us; speedup 1.0000x reference)
//
#include <hip/hip_runtime.h>
#include <hip/hip_bf16.h>

typedef __attribute__((ext_vector_type(4))) float floatx4;
typedef __attribute__((ext_vector_type(8))) short shortx8;

#define HW   1024
#define C    128
#define EPS  1e-8f

// Kernel 1: normalize over channel dim + transpose to fnT[view][p][c] (bf16)
// x: [32 views][128 c][1024 p] fp32.  fnT: [32][1024][128] bf16 (8 MB in d_ws)
__global__ __launch_bounds__(256) void norm_transpose(const float* __restrict__ x,
                                                      __hip_bfloat16* __restrict__ fnT) {
    int g = blockIdx.x * 256 + threadIdx.x;   // g in [0, 32*1024)
    int v = g >> 10;
    int p = g & 1023;
    const float* xv = x + (size_t)v * (C * HW) + p;
    float s = 0.f;
#pragma unroll
    for (int c = 0; c < C; ++c) {
        float val = xv[(size_t)c * HW];      // coalesced: lanes = consecutive p
        s += val * val;
    }
    float scale = 1.0f / (sqrtf(s) + EPS);
    __hip_bfloat16* dst = fnT + (size_t)g * C;
#pragma unroll
    for (int c0 = 0; c0 < C; c0 += 8) {
        shortx8 pack;
#pragma unroll
        for (int u = 0; u < 8; ++u) {
            __hip_bfloat16 h = __float2bfloat16(xv[(size_t)(c0 + u) * HW] * scale);
            pack[u] = *(short*)&h;
        }
        *(shortx8*)(dst + c0) = pack;        // 16B store per thread
    }
}

// Kernel 2: 96 GEMMs C[p,q] = sum_c fnT[vA][p][c] * fnT[vB][q][c]
// m97-style: one-shot K=128 LDS staging via global_load_lds(16B),
// XOR-chunk-swizzled LDS layout (global_load_lds forbids padding; row stride
// 256 B is bank-aligned, so unswizzled b128 reads would be ~8-way conflicted).
// LDS 16B-chunk slot (row, c) holds global chunk (row, c ^ (row&15)).
// Epilogue bounces acc through the (dead) A/B LDS as a 128x128 f32 tile so
// global stores are wave-contiguous dwordx4 streams (full 128B lines) instead
// of 4x64B scattered scalar stores.
struct SmemT {
    union {
        struct { short A[128 * 128]; short B[128 * 128]; } ab;  // 2x 32 KB bf16 tiles
        float tile[128 * 128];                                  // 64 KB f32 out tile
    };
};

__global__ __launch_bounds__(256, 2) void corr_gemm(const __hip_bfloat16* __restrict__ fnT,
                                                    float* __restrict__ out) {
    __shared__ SmemT sm;

    int g = blockIdx.z;          // (b*4 + i)*3 + k
    int b = g / 12;
    int r = g % 12;
    int i = r / 3;
    int k = r % 3;
    int j = k + (k >= i);        // jj[i][k]
    int vA = b * 4 + j;          // provides p (rows)
    int vB = b * 4 + i;          // provides q (cols)

    int lane = threadIdx.x & 63;
    int wave = threadIdx.x >> 6;
    int p0 = blockIdx.y * 128;
    int q0 = blockIdx.x * 128;

    // --- Stage: A/B tiles are contiguous 32 KB slabs of fnT ---
    const char* Ag = (const char*)(fnT + ((size_t)vA * HW + p0) * C);
    const char* Bg = (const char*)(fnT + ((size_t)vB * HW + q0) * C);
    char* Alds = (char*)&sm.ab.A[0];
    char* Blds = (char*)&sm.ab.B[0];
#pragma unroll
    for (int t = 0; t < 8; ++t) {
        int s = (wave * 8 + t) * 64 + lane;          // chunk slot 0..2047
        int row = s >> 4;
        int c16 = s & 15;
        int goff = (row * 16 + (c16 ^ (row & 15))) * 16;
        int loff = (wave * 8 + t) * 1024;            // wave-uniform LDS base
        __builtin_amdgcn_global_load_lds(
            (const __attribute__((address_space(1))) void*)(Ag + goff),
            (__attribute__((address_space(3))) void*)(Alds + loff), 16, 0, 0);
        __builtin_amdgcn_global_load_lds(
            (const __attribute__((address_space(1))) void*)(Bg + goff),
            (__attribute__((address_space(3))) void*)(Blds + loff), 16, 0, 0);
    }
    __syncthreads();   // compiler emits vmcnt(0) drain before s_barrier

    // --- Compute: wave -> 64x64 subtile, 4x4 grid of 16x16x32 MFMA ---
    int wp = (wave >> 1) * 64;
    int wq = (wave & 1) * 64;
    int lr   = lane & 15;
    int quad = lane >> 4;

    const char* Ab = (const char*)&sm.ab.A[0] + (size_t)(wp + lr) * 256;
    const char* Bb = (const char*)&sm.ab.B[0] + (size_t)(wq + lr) * 256;

    floatx4 acc[4][4] = {};

#pragma unroll
    for (int kk = 0; kk < 4; ++kk) {                 // K = 128 in 4 steps of 32
        int co = ((kk * 4 + quad) ^ lr) * 16;        // swizzled chunk offset (row&15 == lr)
        shortx8 a[4], bfr[4];
#pragma unroll
        for (int t = 0; t < 4; ++t) {
            a[t]   = *(const shortx8*)(Ab + t * 16 * 256 + co);
            bfr[t] = *(const shortx8*)(Bb + t * 16 * 256 + co);
        }
#pragma unroll
        for (int mt = 0; mt < 4; ++mt)
#pragma unroll
            for (int nt = 0; nt < 4; ++nt)
                acc[mt][nt] = __builtin_amdgcn_mfma_f32_16x16x32_bf16(a[mt], bfr[nt], acc[mt][nt], 0, 0, 0);
    }

    // --- Epilogue: bounce through LDS, then coalesced dwordx4 streams ---
    // MFMA D layout: col=lane&15, row=quad*4+reg.
    __syncthreads();   // all waves done reading A/B tiles
#pragma unroll
    for (int mt = 0; mt < 4; ++mt) {
#pragma unroll
        for (int rr = 0; rr < 4; ++rr) {
            int row = wp + mt * 16 + quad * 4 + rr;
            int swz = ((row >> 2) & 3) << 4;         // 2-bit XOR: quad spread -> 2-way max
#pragma unroll
            for (int nt = 0; nt < 4; ++nt) {
                int col = wq + nt * 16 + lr;
                sm.tile[row * 128 + (col ^ swz)] = acc[mt][nt][rr];
            }
        }
    }
    __syncthreads();   // tile rows mix data from two waves

    float* outg2 = out + (size_t)g * (HW * HW) + (size_t)p0 * HW + q0;
#pragma unroll
    for (int it = 0; it < 16; ++it) {
        int f = it * 1024 + threadIdx.x * 4;         // flat f32 idx in 128x128 tile
        int row = f >> 7;
        int col = f & 127;                           // multiple of 4
        int swz = ((row >> 2) & 3) << 4;
        floatx4 vv = *(const floatx4*)&sm.tile[row * 128 + (col ^ swz)];
        *(floatx4*)(outg2 + (size_t)row * HW + col) = vv;   // 512B runs, full lines
    }
}

extern "C" void kernel_launch(void* const* d_in, const int* in_sizes, int n_in,
                              void* d_out, int out_size, void* d_ws, size_t ws_size,
                              hipStream_t stream) {
    const float* x = (const float*)d_in[0];
    float* out = (float*)d_out;
    __hip_bfloat16* fnT = (__hip_bfloat16*)d_ws;   // 32*1024*128*2 = 8 MB

    norm_transpose<<<dim3(32 * 1024 / 256), 256, 0, stream>>>(x, fnT);
    corr_gemm<<<dim3(8, 8, 96), 256, 0, stream>>>(fnT, out);
}

// Round 2
// 402.255 us; speedup vs baseline: 1.0256x; 1.0256x over previous
//
#include <hip/hip_runtime.h>
#include <hip/hip_bf16.h>

typedef __attribute__((ext_vector_type(4))) float floatx4;
typedef __attribute__((ext_vector_type(8))) short shortx8;

#define HW   1024
#define C    128
#define EPS  1e-8f

// Kernel 1: normalize over channel dim + transpose to fnT[view][p][c] (bf16)
// x: [32 views][128 c][1024 p] fp32.  fnT: [32][1024][128] bf16 (8 MB in d_ws)
// 64-thread blocks so all 256 CUs participate (was 128 blocks -> half idle).
__global__ __launch_bounds__(64) void norm_transpose(const float* __restrict__ x,
                                                     __hip_bfloat16* __restrict__ fnT) {
    int g = blockIdx.x * 64 + threadIdx.x;    // g in [0, 32*1024)
    int v = g >> 10;
    int p = g & 1023;
    const float* xv = x + (size_t)v * (C * HW) + p;
    float s = 0.f;
#pragma unroll
    for (int c = 0; c < C; ++c) {
        float val = xv[(size_t)c * HW];      // coalesced: lanes = consecutive p
        s += val * val;
    }
    float scale = 1.0f / (sqrtf(s) + EPS);
    __hip_bfloat16* dst = fnT + (size_t)g * C;
#pragma unroll
    for (int c0 = 0; c0 < C; c0 += 8) {
        shortx8 pack;
#pragma unroll
        for (int u = 0; u < 8; ++u) {
            __hip_bfloat16 h = __float2bfloat16(xv[(size_t)(c0 + u) * HW] * scale);
            pack[u] = *(short*)&h;
        }
        *(shortx8*)(dst + c0) = pack;        // 16B store per thread
    }
}

// Kernel 2: 96 GEMMs C[p,q] = sum_c fnT[vA][p][c] * fnT[vB][q][c]
// m97-style one-shot K=128 LDS staging via global_load_lds(16B),
// XOR-chunk-swizzled LDS (global_load_lds forbids padding; row stride 256 B
// is bank-aligned, so unswizzled b128 reads would be ~8-way conflicted).
//
// XCD-chunked grid swizzle: flat 6144-block grid; bid%8 = XCD, bid/8 = chunk
// position. Each XCD walks 12 g's SEQUENTIALLY, so its 64 resident blocks
// share one g's 512 KB fnT slab -> reads stay L2-hit instead of fighting the
// 402 MB write stream on the fabric (read working set was 8 g x 512 KB = 4 MB
// = whole L2 under default round-robin dispatch).
//
// Epilogue: bounce acc through the dead A/B LDS as a 128x128 f32 tile, then
// stream NON-TEMPORAL dwordx4 stores (don't let the write stream evict the
// per-g read working set from L2).
struct SmemT {
    union {
        struct { short A[128 * 128]; short B[128 * 128]; } ab;  // 2x 32 KB bf16 tiles
        float tile[128 * 128];                                  // 64 KB f32 out tile
    };
};

__global__ __launch_bounds__(256, 2) void corr_gemm(const __hip_bfloat16* __restrict__ fnT,
                                                    float* __restrict__ out) {
    __shared__ SmemT sm;

    // --- XCD-chunked swizzle (6144 = 8 XCDs x 768, bijective) ---
    int bid = blockIdx.x;
    int swz = (bid & 7) * 768 + (bid >> 3);
    int g   = swz >> 6;              // block index within: 64 blocks per g
    int rem = swz & 63;
    int p0  = (rem >> 3) << 7;       // (rem/8)*128
    int q0  = (rem & 7) << 7;        // (rem%8)*128

    int b = g / 12;
    int r = g % 12;
    int i = r / 3;
    int k = r % 3;
    int j = k + (k >= i);        // jj[i][k]
    int vA = b * 4 + j;          // provides p (rows)
    int vB = b * 4 + i;          // provides q (cols)

    int lane = threadIdx.x & 63;
    int wave = threadIdx.x >> 6;

    // --- Stage: A/B tiles are contiguous 32 KB slabs of fnT ---
    const char* Ag = (const char*)(fnT + ((size_t)vA * HW + p0) * C);
    const char* Bg = (const char*)(fnT + ((size_t)vB * HW + q0) * C);
    char* Alds = (char*)&sm.ab.A[0];
    char* Blds = (char*)&sm.ab.B[0];
#pragma unroll
    for (int t = 0; t < 8; ++t) {
        int s = (wave * 8 + t) * 64 + lane;          // chunk slot 0..2047
        int row = s >> 4;
        int c16 = s & 15;
        int goff = (row * 16 + (c16 ^ (row & 15))) * 16;
        int loff = (wave * 8 + t) * 1024;            // wave-uniform LDS base
        __builtin_amdgcn_global_load_lds(
            (const __attribute__((address_space(1))) void*)(Ag + goff),
            (__attribute__((address_space(3))) void*)(Alds + loff), 16, 0, 0);
        __builtin_amdgcn_global_load_lds(
            (const __attribute__((address_space(1))) void*)(Bg + goff),
            (__attribute__((address_space(3))) void*)(Blds + loff), 16, 0, 0);
    }
    __syncthreads();   // compiler emits vmcnt(0) drain before s_barrier

    // --- Compute: wave -> 64x64 subtile, 4x4 grid of 16x16x32 MFMA ---
    int wp = (wave >> 1) * 64;
    int wq = (wave & 1) * 64;
    int lr   = lane & 15;
    int quad = lane >> 4;

    const char* Ab = (const char*)&sm.ab.A[0] + (size_t)(wp + lr) * 256;
    const char* Bb = (const char*)&sm.ab.B[0] + (size_t)(wq + lr) * 256;

    floatx4 acc[4][4] = {};

#pragma unroll
    for (int kk = 0; kk < 4; ++kk) {                 // K = 128 in 4 steps of 32
        int co = ((kk * 4 + quad) ^ lr) * 16;        // swizzled chunk offset (row&15 == lr)
        shortx8 a[4], bfr[4];
#pragma unroll
        for (int t = 0; t < 4; ++t) {
            a[t]   = *(const shortx8*)(Ab + t * 16 * 256 + co);
            bfr[t] = *(const shortx8*)(Bb + t * 16 * 256 + co);
        }
#pragma unroll
        for (int mt = 0; mt < 4; ++mt)
#pragma unroll
            for (int nt = 0; nt < 4; ++nt)
                acc[mt][nt] = __builtin_amdgcn_mfma_f32_16x16x32_bf16(a[mt], bfr[nt], acc[mt][nt], 0, 0, 0);
    }

    // --- Epilogue: bounce through LDS, then coalesced non-temporal streams ---
    // MFMA D layout: col=lane&15, row=quad*4+reg.
    __syncthreads();   // all waves done reading A/B tiles
#pragma unroll
    for (int mt = 0; mt < 4; ++mt) {
#pragma unroll
        for (int rr = 0; rr < 4; ++rr) {
            int row = wp + mt * 16 + quad * 4 + rr;
            int swzc = ((row >> 2) & 3) << 4;        // 2-bit XOR: quad spread -> 2-way max
#pragma unroll
            for (int nt = 0; nt < 4; ++nt) {
                int col = wq + nt * 16 + lr;
                sm.tile[row * 128 + (col ^ swzc)] = acc[mt][nt][rr];
            }
        }
    }
    __syncthreads();   // tile rows mix data from two waves

    float* outg2 = out + (size_t)g * (HW * HW) + (size_t)p0 * HW + q0;
#pragma unroll
    for (int it = 0; it < 16; ++it) {
        int f = it * 1024 + threadIdx.x * 4;         // flat f32 idx in 128x128 tile
        int row = f >> 7;
        int col = f & 127;                           // multiple of 4
        int swzc = ((row >> 2) & 3) << 4;
        floatx4 vv = *(const floatx4*)&sm.tile[row * 128 + (col ^ swzc)];
        __builtin_nontemporal_store(vv, (floatx4*)(outg2 + (size_t)row * HW + col));
    }
}

extern "C" void kernel_launch(void* const* d_in, const int* in_sizes, int n_in,
                              void* d_out, int out_size, void* d_ws, size_t ws_size,
                              hipStream_t stream) {
    const float* x = (const float*)d_in[0];
    float* out = (float*)d_out;
    __hip_bfloat16* fnT = (__hip_bfloat16*)d_ws;   // 32*1024*128*2 = 8 MB

    norm_transpose<<<dim3(32 * 1024 / 64), 64, 0, stream>>>(x, fnT);
    corr_gemm<<<dim3(6144), 256, 0, stream>>>(fnT, out);
}